// Round 7
// baseline (253.560 us; speedup 1.0000x reference)
//
#include <hip/hip_runtime.h>
#include <math.h>

#define TOKENS 16384
#define DMODEL 2048
#define NEXP   64
#define TOPK   8
#define WSHORTS 12288        // shorts per 64-k chunk W image (24 frags x 1024 B)

typedef unsigned short u16;
typedef float f32x4 __attribute__((ext_vector_type(4)));
typedef short s16x8 __attribute__((ext_vector_type(8)));

// RNE fp32 -> bf16, also returning the rounded-back fp32 value.
// (bit-identical to the passing R1/R2 kernels' split -> identical logits)
__device__ __forceinline__ u16 f2bf(float f, float& back) {
    unsigned u = __float_as_uint(f);
    unsigned r = u + 0x7fffu + ((u >> 16) & 1u);
    back = __uint_as_float(r & 0xffff0000u);
    return (u16)(r >> 16);
}

// Kernel 1 (unchanged from passing R2): pre-split W into 3 bf16 terms in MFMA
// B-FRAGMENT ORDER: chunk c -> 24 fragments of 1024B, frag(tau,ks,eq) at
// ((tau*2+ks)*4+eq), lane l's 16B = expert eq*16+(l&15), k = c*64+ks*32+(l>>4)*8.
__global__ __launch_bounds__(256) void wconv(
    const float* __restrict__ W, u16* __restrict__ wimg)
{
    const int id  = blockIdx.x * 256 + threadIdx.x;  // 16384 threads
    const int e   = id >> 8;     // expert 0..63
    const int ko8 = id & 255;    // k-oct 0..255
    const int k0  = ko8 * 8;
    const int c   = ko8 >> 3;          // chunk
    const int ks  = (ko8 >> 2) & 1;    // k-half within chunk
    const int hi  = ko8 & 3;           // lane>>4 part
    const int lane = hi * 16 + (e & 15);
    const int eq   = e >> 4;

    const float* src = W + (size_t)e * DMODEL + k0;
    const float4 f0 = *(const float4*)(src);
    const float4 f1 = *(const float4*)(src + 4);
    const float xe[8] = {f0.x, f0.y, f0.z, f0.w, f1.x, f1.y, f1.z, f1.w};
    s16x8 va, vb, vc;
#pragma unroll
    for (int j = 0; j < 8; ++j) {
        float b1, b2, b3;
        const u16 a1 = f2bf(xe[j], b1);
        const float d1 = xe[j] - b1;   // exact (Sterbenz)
        const u16 a2 = f2bf(d1, b2);
        const float d2 = d1 - b2;      // exact
        const u16 a3 = f2bf(d2, b3);
        va[j] = (short)a1; vb[j] = (short)a2; vc[j] = (short)a3;
    }
    u16* base = wimg + (size_t)c * WSHORTS + lane * 8;
    *(s16x8*)(base + ((0 * 2 + ks) * 4 + eq) * 512) = va;
    *(s16x8*)(base + ((1 * 2 + ks) * 4 + eq) * 512) = vb;
    *(s16x8*)(base + ((2 * 2 + ks) * 4 + eq) * 512) = vc;
}

// Kernel 2: BARRIER-FREE fused router.
//  R2's diagnosis: per-chunk LDS double-buffer + __syncthreads lockstep
//  exposed W-load latency every chunk (VGPR=68 proved the compiler sank the
//  prefetch to its use point). Fix: no LDS in the main loop at all.
//  - wave = 16 tokens x 32 experts x K/2: 4096 free-running waves, 4/SIMD
//    (grid 1024x256 all resident), no inter-wave sync until the epilogue.
//  - B fragments read per-wave from the frag-ordered global image: 1KB
//    coalesced per load, L2-resident (768KB image, shared by all waves).
//  - x per-lane global->reg (coalesced 128B/token-row), split in-register.
//  - numerics: f2bf split values, per-(ks,nt) MFMA chain order, and per-64k
//    fp64 flush are BIT-IDENTICAL to the passing R2 kernel; only the fp64
//    k-half combine order differs (~1e-16).
//  - K-halves combine via 16KB LDS 'lg' + ONE barrier, then the verified
//    shuffle top-8 epilogue.
__global__ __launch_bounds__(256, 4) void router_fused(
    const float* __restrict__ x, const u16* __restrict__ wimg,
    const float* __restrict__ bias, float* __restrict__ out_w,
    float* __restrict__ out_i)
{
    __shared__ double lg[2][16][NEXP];   // 16384 B, epilogue only

    const int tid  = threadIdx.x;
    const int lane = tid & 63;
    const int w    = tid >> 6;   // wave 0..3
    const int eh   = w & 1;      // expert half (32 cols)
    const int kh   = w >> 1;     // k half (1024)
    const size_t tokBase = (size_t)blockIdx.x * 16;

    // A-side: lane owns token (lane&15), k-oct lane>>4, k-half kh
    const int arow = lane & 15;
    const float* xrow = x + (tokBase + arow) * (size_t)DMODEL + kh * 1024 +
                        (lane >> 4) * 8;
    // B-side: frag(tau,ks,nt) at wt + ((tau*2+ks)*4 + nt)*512 shorts
    const u16* wt0 = wimg + (size_t)kh * 16 * WSHORTS +
                     (size_t)(eh * 2) * 512 + lane * 8;

    f32x4  acc[2][2];   // [ks][nt]
    double accd[2][4];  // [nt][reg]
#pragma unroll
    for (int i = 0; i < 2; ++i)
#pragma unroll
        for (int j = 0; j < 2; ++j) acc[i][j] = (f32x4){0.f, 0.f, 0.f, 0.f};
#pragma unroll
    for (int j = 0; j < 2; ++j)
#pragma unroll
        for (int r = 0; r < 4; ++r) accd[j][r] = 0.0;

    // prologue: x chunk 0
    float4 xv[4];
    xv[0] = *(const float4*)(xrow);
    xv[1] = *(const float4*)(xrow + 4);
    xv[2] = *(const float4*)(xrow + 32);
    xv[3] = *(const float4*)(xrow + 36);

    for (int t = 0; t < 16; ++t) {
        const u16* wt = wt0 + (size_t)t * WSHORTS;
        // issue all 12 B loads for this chunk (compiler schedules under the
        // 128-VGPR cap; loads are independent of the split below)
        s16x8 b[3][2][2];   // [tau][ks][nt]
#pragma unroll
        for (int tau = 0; tau < 3; ++tau)
#pragma unroll
            for (int ks = 0; ks < 2; ++ks)
#pragma unroll
                for (int nt = 0; nt < 2; ++nt)
                    b[tau][ks][nt] = *(const s16x8*)(
                        wt + ((tau * 2 + ks) * 4 + nt) * 512);

        // split current x regs -> A-fragments (bit-identical to R2)
        s16x8 af[3][2];
#pragma unroll
        for (int ks = 0; ks < 2; ++ks) {
            const float xe[8] = {xv[ks * 2].x,     xv[ks * 2].y,
                                 xv[ks * 2].z,     xv[ks * 2].w,
                                 xv[ks * 2 + 1].x, xv[ks * 2 + 1].y,
                                 xv[ks * 2 + 1].z, xv[ks * 2 + 1].w};
#pragma unroll
            for (int j = 0; j < 8; ++j) {
                float b1, b2, b3;
                const u16 a1 = f2bf(xe[j], b1);
                const float d1 = xe[j] - b1;
                const u16 a2 = f2bf(d1, b2);
                const float d2 = d1 - b2;
                const u16 a3 = f2bf(d2, b3);
                af[0][ks][j] = (short)a1;
                af[1][ks][j] = (short)a2;
                af[2][ks][j] = (short)a3;
            }
        }
        // xv now dead: prefetch next chunk's x (full-chunk latency window)
        if (t + 1 < 16) {
            const float* xp = xrow + (size_t)(t + 1) * 64;
            xv[0] = *(const float4*)(xp);
            xv[1] = *(const float4*)(xp + 4);
            xv[2] = *(const float4*)(xp + 32);
            xv[3] = *(const float4*)(xp + 36);
        }
        // MFMA: chain order per (ks,nt) identical to the passing kernel
#pragma unroll
        for (int ks = 0; ks < 2; ++ks)
#pragma unroll
            for (int nt = 0; nt < 2; ++nt) {
                f32x4 t0 = acc[ks][nt];
                t0 = __builtin_amdgcn_mfma_f32_16x16x32_bf16(af[0][ks], b[0][ks][nt], t0, 0, 0, 0);
                t0 = __builtin_amdgcn_mfma_f32_16x16x32_bf16(af[0][ks], b[1][ks][nt], t0, 0, 0, 0);
                t0 = __builtin_amdgcn_mfma_f32_16x16x32_bf16(af[1][ks], b[0][ks][nt], t0, 0, 0, 0);
                t0 = __builtin_amdgcn_mfma_f32_16x16x32_bf16(af[0][ks], b[2][ks][nt], t0, 0, 0, 0);
                t0 = __builtin_amdgcn_mfma_f32_16x16x32_bf16(af[2][ks], b[0][ks][nt], t0, 0, 0, 0);
                t0 = __builtin_amdgcn_mfma_f32_16x16x32_bf16(af[1][ks], b[1][ks][nt], t0, 0, 0, 0);
                acc[ks][nt] = t0;
            }
        // fp64 flush once per 64-k chunk (identical to R2)
#pragma unroll
        for (int nt = 0; nt < 2; ++nt)
#pragma unroll
            for (int r = 0; r < 4; ++r) {
                accd[nt][r] += (double)acc[0][nt][r] + (double)acc[1][nt][r];
                acc[0][nt][r] = 0.f;
                acc[1][nt][r] = 0.f;
            }
    }

    // epilogue: k-half exchange (ONE barrier in the whole kernel)
    // C/D mapping (m89): token row = (lane>>4)*4 + r, expert col = lane&15
#pragma unroll
    for (int nt = 0; nt < 2; ++nt)
#pragma unroll
        for (int r = 0; r < 4; ++r) {
            const int row = (lane >> 4) * 4 + r;
            const int col = eh * 32 + nt * 16 + (lane & 15);
            lg[kh][row][col] = accd[nt][r];
        }
    __syncthreads();

    // fused top-8: wave handles 4 tokens, lane = expert (verified epilogue)
    const float be = bias[lane];
#pragma unroll
    for (int i = 0; i < 4; ++i) {
        const int tl = w * 4 + i;
        float v = (float)(lg[0][tl][lane] + lg[1][tl][lane]) + be;
        const int myi = lane;
        float bv = 0.0f; int bi = 0;
#pragma unroll
        for (int r = 0; r < TOPK; ++r) {
            float mv = v; int mi = myi;
#pragma unroll
            for (int off = 32; off > 0; off >>= 1) {
                const float ov = __shfl_xor(mv, off, 64);
                const int   oi = __shfl_xor(mi, off, 64);
                if (ov > mv || (ov == mv && oi < mi)) { mv = ov; mi = oi; }
            }
            if (lane == r) { bv = mv; bi = mi; }
            if (myi == mi) { v = -INFINITY; }
        }
        if (lane < TOPK) {
            const size_t tok = tokBase + tl;
            out_w[tok * TOPK + lane] = 1.0f / (1.0f + expf(-bv));
            out_i[tok * TOPK + lane] = (float)bi;
        }
    }
}

extern "C" void kernel_launch(void* const* d_in, const int* in_sizes, int n_in,
                              void* d_out, int out_size, void* d_ws, size_t ws_size,
                              hipStream_t stream) {
    const float* x    = (const float*)d_in[0];   // [4,4096,2048]
    const float* W    = (const float*)d_in[1];   // [64,2048]
    const float* bias = (const float*)d_in[2];   // [64]
    float* out_w = (float*)d_out;                          // [16384,8]
    float* out_i = (float*)d_out + (size_t)TOKENS * TOPK;  // [16384,8] as float
    u16* wimg = (u16*)d_ws;  // 32 * 24576 B = 786432 B, fragment-ordered

    wconv<<<dim3((NEXP * DMODEL / 8) / 256), 256, 0, stream>>>(W, wimg);
    router_fused<<<dim3(TOKENS / 16), 256, 0, stream>>>(x, wimg, bias, out_w, out_i);
}